// Round 5
// baseline (238.539 us; speedup 1.0000x reference)
//
#include <hip/hip_runtime.h>
#include <hip/hip_bf16.h>
#include <math.h>

#define LTOT   4096
#define EDIM   64
#define NMODES 64
#define BH     256
#define TWO_PI 6.28318530717958647692f

typedef float f32x4 __attribute__((ext_vector_type(4)));
typedef short s16x8 __attribute__((ext_vector_type(8)));

__device__ inline unsigned short f2bf(float f) {
    unsigned u = __builtin_bit_cast(unsigned, f);
    u += 0x7fff + ((u >> 16) & 1);           // round-to-nearest-even
    return (unsigned short)(u >> 16);
}
// compiler-friendly pack: emits v_cvt_pk_bf16_f32
__device__ inline unsigned packbf(float lo, float hi) {
    float2 t; t.x = lo; t.y = hi;
    __hip_bfloat162 h = __float22bfloat162_rn(t);
    unsigned r;
    __builtin_memcpy(&r, &h, 4);
    return r;
}
__device__ inline float bf2f(unsigned lo16) {
    return __builtin_bit_cast(float, lo16 << 16);
}

// ---------- Tables ----------
// Tm[m=128][l=4096] bf16: Tm[2k][l]=cos, Tm[2k+1][l]=-sin  (forward DFT)
__global__ void k_tab_m(const int* __restrict__ index, unsigned short* __restrict__ Tm) {
    int k = blockIdx.x;
    int f = index[k];
    for (int l = threadIdx.x; l < LTOT; l += blockDim.x) {
        int m = (f * l) & (LTOT - 1);
        float th = (float)m * (TWO_PI / (float)LTOT);
        float s, c; sincosf(th, &s, &c);
        Tm[(size_t)(2 * k) * LTOT + l]     = f2bf(c);
        Tm[(size_t)(2 * k + 1) * LTOT + l] = f2bf(-s);
    }
}
// Tt[l=4096][m=128] bf16: Tt[l][2k]=cos, Tt[l][2k+1]=sin  (inverse DFT)
__global__ void k_tab_t(const int* __restrict__ index, unsigned short* __restrict__ Tt) {
    int l = blockIdx.x * 4 + (threadIdx.x >> 6);
    int k = threadIdx.x & 63;
    int f = index[k];
    int m = (f * l) & (LTOT - 1);
    float th = (float)m * (TWO_PI / (float)LTOT);
    float s, c; sincosf(th, &s, &c);
    ((unsigned*)Tt)[l * 64 + k] = packbf(c, s);
}
// wt[i] = packbf(w[2i], w[2i+1]) : natural [e][o][k] complex -> bf16 pair
__global__ void k_wtab(const float* __restrict__ w, unsigned* __restrict__ wt) {
    int i = blockIdx.x * 256 + threadIdx.x;
    float2 v = ((const float2*)w)[i];
    wt[i] = packbf(v.x, v.y);
}

// ---------- Fused: per-(b,h) block: DFT -> mode-mix -> iDFT ----------
// grid = 256 blocks (one bh per CU), 1024 threads (16 waves).
__global__ __launch_bounds__(1024, 1) void k_fused(const float* __restrict__ x,
                                                   const unsigned short* __restrict__ Tm,
                                                   const unsigned short* __restrict__ Tt,
                                                   const unsigned* __restrict__ wtab,
                                                   const int* __restrict__ index,
                                                   float* __restrict__ y) {
    int bh = blockIdx.x;
    const float* xb = x + (size_t)bh * LTOT * EDIM;

    __shared__ unsigned xT[64 * 68];    // 17.4 KB  [e][lp] swizzled bf16-pairs
    __shared__ float    Xs[64 * 132];   // 33.8 KB  [e][m] spectrum (interleaved Re/Im)
    __shared__ unsigned ABl[64 * 68];   // 17.4 KB  [o][k] coeff bf16-pairs (cos,sin)

    int t = threadIdx.x;
    int lane = t & 63, w = t >> 6;
    int r = lane & 15, kb8 = lane >> 4;
    int es = w & 3, ms = w >> 2;

    // ================= Phase A: X[e][m] = sum_l x[l,e] * T[l,m] =================
    int lp = t >> 4;                      // 0..63 (l-pair row)
    int q  = t & 15;                      // e-quad
    unsigned swzW = ((unsigned)(q & 7)) << 2;
    unsigned swzR = (((unsigned)(es & 1)) << 4) + (((unsigned)(r >> 2)) << 2);

    f32x4 acc[2]; acc[0] = (f32x4)0.f; acc[1] = (f32x4)0.f;

    float4 a0, a1;
    {
        const float* b0 = xb + (size_t)(2 * lp) * EDIM + 4 * q;
        a0 = *(const float4*)b0;
        a1 = *(const float4*)(b0 + EDIM);
    }
    for (int tile = 0; tile < 32; ++tile) {
        int l0 = tile * 128;
        {   // regs -> LDS (bf16 pack, swizzled)  [2-way banks: free]
            float A0[4] = {a0.x, a0.y, a0.z, a0.w};
            float A1[4] = {a1.x, a1.y, a1.z, a1.w};
            #pragma unroll
            for (int j = 0; j < 4; ++j) {
                int e = 4 * q + j;
                xT[e * 68 + ((unsigned)lp ^ swzW)] = packbf(A0[j], A1[j]);
            }
        }
        __syncthreads();
        if (tile + 1 < 32) {   // T14: issue next tile's loads now, consume next iter
            const float* b0 = xb + (size_t)(l0 + 128 + 2 * lp) * EDIM + 4 * q;
            a0 = *(const float4*)b0;
            a1 = *(const float4*)(b0 + EDIM);
        }
        #pragma unroll
        for (int kk = 0; kk < 4; ++kk) {
            s16x8 af = *(const s16x8*)(xT + (es * 16 + r) * 68 +
                                       (((unsigned)(kk * 16 + kb8 * 4)) ^ swzR));
            #pragma unroll
            for (int ns = 0; ns < 2; ++ns) {
                int m = ms * 32 + ns * 16 + r;
                s16x8 bf = *(const s16x8*)(Tm + (size_t)m * LTOT + l0 + kk * 32 + kb8 * 8);
                acc[ns] = __builtin_amdgcn_mfma_f32_16x16x32_bf16(af, bf, acc[ns], 0, 0, 0);
            }
        }
        __syncthreads();
    }
    // acc -> Xs   (D: row e = es*16 + kb8*4+g, col m = ms*32 + ns*16 + r)
    #pragma unroll
    for (int ns = 0; ns < 2; ++ns)
        #pragma unroll
        for (int g = 0; g < 4; ++g)
            Xs[(es * 16 + kb8 * 4 + g) * 132 + ms * 32 + ns * 16 + r] = acc[ns][g];
    __syncthreads();

    // ================= Phase B: mode mix (complex 64x64 per k) =================
    {
        int k = lane;                     // 0..63 per wave
        int og = w;                       // wave owns o = og*4 .. og*4+3
        int f = index[k];
        float cc = (f == 0 ? 1.0f : 2.0f) / (float)LTOT;
        float aR[4] = {}, aI[4] = {};
        for (int e = 0; e < 64; ++e) {
            float2 X = *(const float2*)&Xs[e * 132 + 2 * k];
            #pragma unroll
            for (int oi = 0; oi < 4; ++oi) {
                unsigned wv = wtab[((size_t)(e * 64 + og * 4 + oi)) * 64 + k];
                float wr = bf2f(wv & 0xffffu);
                float wi = bf2f(wv >> 16);
                aR[oi] += X.x * wr - X.y * wi;
                aI[oi] += X.x * wi + X.y * wr;
            }
        }
        #pragma unroll
        for (int oi = 0; oi < 4; ++oi) {
            int o = og * 4 + oi;
            float im = (f == 0) ? 0.0f : -cc * aI[oi];
            ABl[o * 68 + k] = packbf(cc * aR[oi], im);
        }
    }
    __syncthreads();

    // ================= Phase C: y[l][o] = sum_m AB[o][m] * Tt[l][m] =================
    s16x8 afr[4][4];                      // [o-slice][k-chunk], o = es2*16 + r
    #pragma unroll
    for (int es2 = 0; es2 < 4; ++es2)
        #pragma unroll
        for (int ks = 0; ks < 4; ++ks)
            afr[es2][ks] = *(const s16x8*)(ABl + (es2 * 16 + r) * 68 + ks * 16 + kb8 * 4);

    for (int it = 0; it < 16; ++it) {
        int ltile = w * 256 + it * 16;
        s16x8 btf[4];
        #pragma unroll
        for (int ks = 0; ks < 4; ++ks)
            btf[ks] = *(const s16x8*)(Tt + (size_t)(ltile + r) * 128 + ks * 32 + kb8 * 8);
        f32x4 oa[4];
        #pragma unroll
        for (int es2 = 0; es2 < 4; ++es2) oa[es2] = (f32x4)0.f;
        #pragma unroll
        for (int ks = 0; ks < 4; ++ks)
            #pragma unroll
            for (int es2 = 0; es2 < 4; ++es2)
                oa[es2] = __builtin_amdgcn_mfma_f32_16x16x32_bf16(afr[es2][ks], btf[ks], oa[es2], 0, 0, 0);
        // D: row = o = es2*16 + kb8*4+g, col = l = ltile + r -> contiguous f32x4 along o
        float* yb = y + ((size_t)bh * LTOT + ltile + r) * EDIM;
        #pragma unroll
        for (int es2 = 0; es2 < 4; ++es2)
            *(f32x4*)(yb + es2 * 16 + kb8 * 4) = oa[es2];
    }
}

extern "C" void kernel_launch(void* const* d_in, const int* in_sizes, int n_in,
                              void* d_out, int out_size, void* d_ws, size_t ws_size,
                              hipStream_t stream) {
    const float* x     = (const float*)d_in[0];
    const float* wgt   = (const float*)d_in[1];
    const int*   index = (const int*)d_in[2];
    float* y  = (float*)d_out;
    float* ws = (float*)d_ws;

    // ws layout (float offsets): Tm 1MB | Tt 1MB | wt 1MB
    unsigned short* Tm = (unsigned short*)ws;
    unsigned short* Tt = (unsigned short*)(ws + 262144);
    unsigned*       wt = (unsigned*)(ws + 524288);

    hipLaunchKernelGGL(k_tab_m, dim3(NMODES), dim3(256), 0, stream, index, Tm);
    hipLaunchKernelGGL(k_tab_t, dim3(1024),   dim3(256), 0, stream, index, Tt);
    hipLaunchKernelGGL(k_wtab,  dim3(1024),   dim3(256), 0, stream, wgt, wt);
    hipLaunchKernelGGL(k_fused, dim3(BH),     dim3(1024), 0, stream, x, Tm, Tt, wt, index, y);
}

// Round 6
// 220.651 us; speedup vs baseline: 1.0811x; 1.0811x over previous
//
#include <hip/hip_runtime.h>
#include <hip/hip_bf16.h>
#include <math.h>

#define LTOT   4096
#define EDIM   64
#define NMODES 64
#define BH     256
#define TWO_PI 6.28318530717958647692f

typedef float f32x4 __attribute__((ext_vector_type(4)));
typedef short s16x8 __attribute__((ext_vector_type(8)));

__device__ inline unsigned short f2bf(float f) {
    unsigned u = __builtin_bit_cast(unsigned, f);
    u += 0x7fff + ((u >> 16) & 1);           // round-to-nearest-even
    return (unsigned short)(u >> 16);
}
// compiler-friendly pack: emits v_cvt_pk_bf16_f32
__device__ inline unsigned packbf(float lo, float hi) {
    float2 t; t.x = lo; t.y = hi;
    __hip_bfloat162 h = __float22bfloat162_rn(t);
    unsigned r;
    __builtin_memcpy(&r, &h, 4);
    return r;
}
__device__ inline float bf2f(unsigned lo16) {
    return __builtin_bit_cast(float, lo16 << 16);
}

// ---------- Tables ----------
// Tm[m=128][l=4096] bf16: Tm[2k][l]=cos, Tm[2k+1][l]=-sin  (forward DFT)
__global__ void k_tab_m(const int* __restrict__ index, unsigned short* __restrict__ Tm) {
    int k = blockIdx.x;
    int f = index[k];
    for (int l = threadIdx.x; l < LTOT; l += blockDim.x) {
        int m = (f * l) & (LTOT - 1);
        float th = (float)m * (TWO_PI / (float)LTOT);
        float s, c; sincosf(th, &s, &c);
        Tm[(size_t)(2 * k) * LTOT + l]     = f2bf(c);
        Tm[(size_t)(2 * k + 1) * LTOT + l] = f2bf(-s);
    }
}
// Tt[l=4096][m=128] bf16: Tt[l][2k]=cos, Tt[l][2k+1]=sin  (inverse DFT)
__global__ void k_tab_t(const int* __restrict__ index, unsigned short* __restrict__ Tt) {
    int l = blockIdx.x * 4 + (threadIdx.x >> 6);
    int k = threadIdx.x & 63;
    int f = index[k];
    int m = (f * l) & (LTOT - 1);
    float th = (float)m * (TWO_PI / (float)LTOT);
    float s, c; sincosf(th, &s, &c);
    ((unsigned*)Tt)[l * 64 + k] = packbf(c, s);
}
// wt[i] = packbf(w[2i], w[2i+1]) : natural [e][o][k] complex -> bf16 pair
__global__ void k_wtab(const float* __restrict__ w, unsigned* __restrict__ wt) {
    int i = blockIdx.x * 256 + threadIdx.x;
    float2 v = ((const float2*)w)[i];
    wt[i] = packbf(v.x, v.y);
}

// ---------- Stage 1: X[e][m] = sum_l xT[e][l] * T[l][m]  (MFMA bf16) ----------
// grid = BH*4 (bh, quarter-of-L partial), 256 threads (4 waves: 2 e-halves x 2 m-halves).
// Double-buffered LDS, 1 barrier/tile, x prefetched to regs (T14).
__global__ __launch_bounds__(256, 4) void k_stage1(const float* __restrict__ x,
                                                   const unsigned short* __restrict__ Tm,
                                                   float* __restrict__ Xp) {
    int bh = blockIdx.x >> 2, part = blockIdx.x & 3;
    const float* xb = x + ((size_t)bh * LTOT + part * 1024) * EDIM;
    __shared__ unsigned xT[2][64 * 68];           // [e=64][64+4 u32], XOR-swizzled

    int t = threadIdx.x;
    int q = t & 15, lp0 = t >> 4;                 // loader role (lp0 0..15)
    int lane = t & 63, w = t >> 6;                // mfma role
    int r = lane & 15, kb8 = lane >> 4;
    int es = w & 1, ms = w >> 1;                  // e-half, m-half
    unsigned swzW = ((unsigned)(q & 7)) << 2;

    f32x4 acc[2][4];
    #pragma unroll
    for (int i = 0; i < 2; ++i)
        #pragma unroll
        for (int n = 0; n < 4; ++n) acc[i][n] = (f32x4)0.f;

    float4 xn[8];
    // prologue: load + stage tile 0
    #pragma unroll
    for (int p = 0; p < 4; ++p) {
        const float* b = xb + (size_t)(2 * (lp0 + p * 16)) * EDIM + 4 * q;
        xn[2 * p]     = *(const float4*)b;
        xn[2 * p + 1] = *(const float4*)(b + EDIM);
    }
    #pragma unroll
    for (int p = 0; p < 4; ++p) {
        float A0[4] = {xn[2*p].x, xn[2*p].y, xn[2*p].z, xn[2*p].w};
        float A1[4] = {xn[2*p+1].x, xn[2*p+1].y, xn[2*p+1].z, xn[2*p+1].w};
        #pragma unroll
        for (int j = 0; j < 4; ++j)
            xT[0][(4 * q + j) * 68 + (((unsigned)(lp0 + p * 16)) ^ swzW)] = packbf(A0[j], A1[j]);
    }
    __syncthreads();

    for (int t8 = 0; t8 < 8; ++t8) {
        int cur = t8 & 1;
        if (t8 < 7) {          // T14: issue next tile's global loads now
            const float* tb = xb + (size_t)((t8 + 1) * 128) * EDIM;
            #pragma unroll
            for (int p = 0; p < 4; ++p) {
                const float* b = tb + (size_t)(2 * (lp0 + p * 16)) * EDIM + 4 * q;
                xn[2 * p]     = *(const float4*)b;
                xn[2 * p + 1] = *(const float4*)(b + EDIM);
            }
        }
        // compute tile t8 from buf[cur]
        #pragma unroll
        for (int kk = 0; kk < 4; ++kk) {
            s16x8 af[2];
            #pragma unroll
            for (int sub = 0; sub < 2; ++sub) {
                int row = es * 32 + sub * 16 + r;
                unsigned swz = (((unsigned)sub) << 4) + (((unsigned)(r >> 2)) << 2);
                af[sub] = *(const s16x8*)(xT[cur] + row * 68 + (((unsigned)(kk * 16 + kb8 * 4)) ^ swz));
            }
            #pragma unroll
            for (int ns = 0; ns < 4; ++ns) {
                int m = ms * 64 + ns * 16 + r;
                s16x8 bf = *(const s16x8*)(Tm + (size_t)m * LTOT + part * 1024 + t8 * 128 + kk * 32 + kb8 * 8);
                acc[0][ns] = __builtin_amdgcn_mfma_f32_16x16x32_bf16(af[0], bf, acc[0][ns], 0, 0, 0);
                acc[1][ns] = __builtin_amdgcn_mfma_f32_16x16x32_bf16(af[1], bf, acc[1][ns], 0, 0, 0);
            }
        }
        if (t8 < 7) {          // stage next tile into other buffer
            #pragma unroll
            for (int p = 0; p < 4; ++p) {
                float A0[4] = {xn[2*p].x, xn[2*p].y, xn[2*p].z, xn[2*p].w};
                float A1[4] = {xn[2*p+1].x, xn[2*p+1].y, xn[2*p+1].z, xn[2*p+1].w};
                #pragma unroll
                for (int j = 0; j < 4; ++j)
                    xT[cur ^ 1][(4 * q + j) * 68 + (((unsigned)(lp0 + p * 16)) ^ swzW)] = packbf(A0[j], A1[j]);
            }
        }
        __syncthreads();
    }

    // D: row e = es*32 + sub*16 + kb8*4+g, col m = ms*64 + ns*16 + r
    float* Xb = Xp + ((size_t)part * BH + bh) * (64 * 128);
    #pragma unroll
    for (int sub = 0; sub < 2; ++sub)
        #pragma unroll
        for (int ns = 0; ns < 4; ++ns)
            #pragma unroll
            for (int g = 0; g < 4; ++g)
                Xb[(es * 32 + sub * 16 + kb8 * 4 + g) * 128 + ms * 64 + ns * 16 + r] = acc[sub][ns][g];
}

// ---------- Stage 2+3 fused: mode mix -> iDFT ----------
// grid = BH (one bh per block), 512 threads (8 waves, 2 blocks/CU).
__global__ __launch_bounds__(512, 4) void k_stage23(const float* __restrict__ Xp,
                                                    const unsigned* __restrict__ wtab,
                                                    const unsigned short* __restrict__ Tt,
                                                    const int* __restrict__ index,
                                                    float* __restrict__ y) {
    int bh = blockIdx.x;
    __shared__ float XsR[64 * 68];      // 17.4 KB  Re plane [e][k]
    __shared__ float XsI[64 * 68];      // 17.4 KB  Im plane [e][k]
    __shared__ unsigned ABl[64 * 68];   // 17.4 KB  [o][k] coeff bf16-pairs (cos,sin)

    int t = threadIdx.x;
    int lane = t & 63, w = t >> 6;      // w 0..7
    int r = lane & 15, kb8 = lane >> 4;

    // ---- load & sum Xp parts, deinterleave into Re/Im planes ----
    #pragma unroll
    for (int i = 0; i < 4; ++i) {
        int idx = t + i * 512;          // f32x4 index over [64 e][32]
        f32x4 v = (f32x4)0.f;
        #pragma unroll
        for (int p = 0; p < 4; ++p)
            v += ((const f32x4*)(Xp + ((size_t)p * BH + bh) * 8192))[idx];
        int e = idx >> 5, k0 = (idx & 31) * 2;
        XsR[e * 68 + k0]     = v.x;
        XsI[e * 68 + k0]     = v.y;
        XsR[e * 68 + k0 + 1] = v.z;
        XsI[e * 68 + k0 + 1] = v.w;
    }
    __syncthreads();

    // ---- Phase B: mode mix (complex 64x64 per k), wave w owns o = w*8..w*8+7 ----
    {
        int k = lane;
        int f = index[k];
        float cc = (f == 0 ? 1.0f : 2.0f) / (float)LTOT;
        int o0 = w * 8;
        float aR[8] = {}, aI[8] = {};
        for (int e = 0; e < 64; ++e) {
            float xr = XsR[e * 68 + k];
            float xi = XsI[e * 68 + k];
            #pragma unroll
            for (int oi = 0; oi < 8; ++oi) {
                unsigned wv = wtab[((size_t)(e * 64 + o0 + oi)) * 64 + k];
                float wr = bf2f(wv & 0xffffu);
                float wi = bf2f(wv >> 16);
                aR[oi] += xr * wr - xi * wi;
                aI[oi] += xr * wi + xi * wr;
            }
        }
        #pragma unroll
        for (int oi = 0; oi < 8; ++oi) {
            float im = (f == 0) ? 0.0f : -cc * aI[oi];
            ABl[(o0 + oi) * 68 + k] = packbf(cc * aR[oi], im);
        }
    }
    __syncthreads();

    // ---- Phase C: y[l][o] = sum_m AB[o][m] * Tt[l][m], barrier-free ----
    s16x8 afr[4][4];                    // [o-slice][k-chunk], o = es2*16 + r
    #pragma unroll
    for (int es2 = 0; es2 < 4; ++es2)
        #pragma unroll
        for (int ks = 0; ks < 4; ++ks)
            afr[es2][ks] = *(const s16x8*)((const unsigned short*)ABl +
                                           (es2 * 16 + r) * 136 + ks * 32 + kb8 * 8);

    for (int it = 0; it < 32; ++it) {
        int ltile = w * 512 + it * 16;
        s16x8 btf[4];
        #pragma unroll
        for (int ks = 0; ks < 4; ++ks)
            btf[ks] = *(const s16x8*)(Tt + (size_t)(ltile + r) * 128 + ks * 32 + kb8 * 8);
        f32x4 oa[4];
        #pragma unroll
        for (int es2 = 0; es2 < 4; ++es2) oa[es2] = (f32x4)0.f;
        #pragma unroll
        for (int ks = 0; ks < 4; ++ks)
            #pragma unroll
            for (int es2 = 0; es2 < 4; ++es2)
                oa[es2] = __builtin_amdgcn_mfma_f32_16x16x32_bf16(afr[es2][ks], btf[ks], oa[es2], 0, 0, 0);
        // D: row = o = es2*16 + kb8*4+g, col = l = ltile + r -> contiguous f32x4 along o
        float* yb = y + ((size_t)bh * LTOT + ltile + r) * EDIM;
        #pragma unroll
        for (int es2 = 0; es2 < 4; ++es2)
            *(f32x4*)(yb + es2 * 16 + kb8 * 4) = oa[es2];
    }
}

extern "C" void kernel_launch(void* const* d_in, const int* in_sizes, int n_in,
                              void* d_out, int out_size, void* d_ws, size_t ws_size,
                              hipStream_t stream) {
    const float* x     = (const float*)d_in[0];
    const float* wgt   = (const float*)d_in[1];
    const int*   index = (const int*)d_in[2];
    float* y  = (float*)d_out;
    float* ws = (float*)d_ws;

    // ws layout (float offsets): Tm 1MB | Tt 1MB | wt 1MB | Xp 32MB
    unsigned short* Tm = (unsigned short*)ws;
    unsigned short* Tt = (unsigned short*)(ws + 262144);
    unsigned*       wt = (unsigned*)(ws + 524288);
    float*          Xp = ws + 786432;

    hipLaunchKernelGGL(k_tab_m,   dim3(NMODES), dim3(256), 0, stream, index, Tm);
    hipLaunchKernelGGL(k_tab_t,   dim3(1024),   dim3(256), 0, stream, index, Tt);
    hipLaunchKernelGGL(k_wtab,    dim3(1024),   dim3(256), 0, stream, wgt, wt);
    hipLaunchKernelGGL(k_stage1,  dim3(BH * 4), dim3(256), 0, stream, x, Tm, Xp);
    hipLaunchKernelGGL(k_stage23, dim3(BH),     dim3(512), 0, stream, Xp, wt, Tt, index, y);
}